// Round 11
// baseline (3180.132 us; speedup 1.0000x reference)
//
#include <hip/hip_runtime.h>
#include <hip/hip_cooperative_groups.h>

namespace cg = cooperative_groups;

#define NN 100000
#define NE 3200000
#define NB 1021        // buckets
#define BNODES 98      // nodes per bucket (98*1021 >= NN)
#define NBLK 256       // partition blocks
#define CH 12500       // edges per partition block (NBLK*CH == NE)
#define NCHUNK 8       // src chunks (12500 nodes, 3.2MB bf16 slice @128ch)
#define AGG_BLOCKS 1024 // 4 blocks/CU co-resident

typedef unsigned int uint;

// ---- bf16 helpers (RTNE) ----
__device__ inline uint bfr(float f) {
  uint u = __float_as_uint(f);
  return (u + 0x7fffu + ((u >> 16) & 1u)) >> 16;
}
__device__ inline uint packbf(float a, float b) { return bfr(a) | (bfr(b) << 16); }
__device__ inline void addq(uint4 q, float* a) {
  uint u[4] = {q.x, q.y, q.z, q.w};
#pragma unroll
  for (int j = 0; j < 4; ++j) {
    a[2 * j]     += __uint_as_float(u[j] << 16);
    a[2 * j + 1] += __uint_as_float(u[j] & 0xffff0000u);
  }
}
// chunk = s / 12500 via magic multiply (exact for s < 2^17)
__device__ inline int chunk8(int s) {
  return (int)(((unsigned long long)(uint)s * 343598ull) >> 32);
}

// ---------------- P1: per-block bucket histogram ----------------
__global__ __launch_bounds__(256) void pcount_kernel(const int* __restrict__ dst,
                                                     int* __restrict__ cntmat) {
  __shared__ int cnt[NB];
  int bk = blockIdx.x, tid = threadIdx.x;
  for (int j = tid; j < NB; j += 256) cnt[j] = 0;
  __syncthreads();
  int base = bk * CH;
  for (int i = base + tid * 4; i < base + CH; i += 1024) {
    int4 d4 = *(const int4*)&dst[i];
    atomicAdd(&cnt[(uint)d4.x / (uint)BNODES], 1);
    atomicAdd(&cnt[(uint)d4.y / (uint)BNODES], 1);
    atomicAdd(&cnt[(uint)d4.z / (uint)BNODES], 1);
    atomicAdd(&cnt[(uint)d4.w / (uint)BNODES], 1);
  }
  __syncthreads();
  for (int j = tid; j < NB; j += 256) cntmat[(size_t)j * NBLK + bk] = cnt[j];
}

// ---------------- P2a: bucket totals ----------------
__global__ __launch_bounds__(256) void rowsum_kernel(const int* __restrict__ cntmat,
                                                     int* __restrict__ btotal) {
  int b = blockIdx.x, t = threadIdx.x;
  int v = cntmat[(size_t)b * NBLK + t];
#pragma unroll
  for (int off = 32; off >= 1; off >>= 1) v += __shfl_xor(v, off, 64);
  __shared__ int ws[4];
  if ((t & 63) == 0) ws[t >> 6] = v;
  __syncthreads();
  if (t == 0) btotal[b] = ws[0] + ws[1] + ws[2] + ws[3];
}

// ---------------- P2b: scan bucket totals -> bases ----------------
__global__ __launch_bounds__(1024) void bucket_scan_kernel(const int* __restrict__ btotal,
                                                           int* __restrict__ bbase) {
  __shared__ int sh[1024];
  int i = threadIdx.x;
  int v = (i < NB) ? btotal[i] : 0;
  sh[i] = v;
  __syncthreads();
  for (int off = 1; off < 1024; off <<= 1) {
    int t = (i >= off) ? sh[i - off] : 0;
    __syncthreads();
    sh[i] += t;
    __syncthreads();
  }
  if (i < NB) bbase[i] = sh[i] - v;
}

// ---------------- P2c: per-(bucket,block) offsets ----------------
__global__ __launch_bounds__(256) void offsets_kernel(const int* __restrict__ cntmat,
                                                      const int* __restrict__ bbase,
                                                      int* __restrict__ offmat) {
  __shared__ int sh[256];
  int b = blockIdx.x, t = threadIdx.x;
  int v = cntmat[(size_t)b * NBLK + t];
  sh[t] = v;
  __syncthreads();
  for (int off = 1; off < 256; off <<= 1) {
    int u = (t >= off) ? sh[t - off] : 0;
    __syncthreads();
    sh[t] += u;
    __syncthreads();
  }
  offmat[(size_t)b * NBLK + t] = bbase[b] + sh[t] - v;
}

// ---------------- P3: scatter into bucket-contiguous store (packed 4B) ----------------
__global__ __launch_bounds__(256) void pscatter_kernel(const int* __restrict__ src,
                                                       const int* __restrict__ dst,
                                                       const int* __restrict__ offmat,
                                                       int* __restrict__ store) {
  __shared__ int lcur[NB];
  int bk = blockIdx.x, tid = threadIdx.x;
  for (int j = tid; j < NB; j += 256) lcur[j] = offmat[(size_t)j * NBLK + bk];
  __syncthreads();
  int base = bk * CH;
  for (int i = base + tid * 4; i < base + CH; i += 1024) {
    int4 d4 = *(const int4*)&dst[i];
    int4 s4 = *(const int4*)&src[i];
    int dd[4] = {d4.x, d4.y, d4.z, d4.w};
    int ss[4] = {s4.x, s4.y, s4.z, s4.w};
#pragma unroll
    for (int j = 0; j < 4; ++j) {
      uint b = (uint)dd[j] / (uint)BNODES;
      int dl = dd[j] - (int)(b * BNODES);
      int pos = atomicAdd(&lcur[b], 1);
      store[pos] = ss[j] | (dl << 17);
    }
  }
}

// ---------------- P4: per-bucket chunk-major CSR + packed rcp + dinv ----------------
// bin = c*BNODES + dl; rcp[node*8+c] = (abs_start<<8)|len
__global__ __launch_bounds__(256) void build_kernel(const int* __restrict__ btotal,
                                                    const int* __restrict__ bbase,
                                                    const int* __restrict__ store,
                                                    int* __restrict__ rcp,
                                                    float* __restrict__ dinv,
                                                    int* __restrict__ csr_src) {
  __shared__ int cnt2[NCHUNK * BNODES];
  __shared__ int excl2[NCHUNK * BNODES];
  int b = blockIdx.x, tid = threadIdx.x;
  int nb0 = b * BNODES;
  int nn = min(BNODES, NN - nb0);
  for (int j = tid; j < NCHUNK * BNODES; j += 256) cnt2[j] = 0;
  __syncthreads();
  int sz = btotal[b], bb = bbase[b];
  const int* bs = store + bb;
  for (int e = tid; e < sz; e += 256) {
    int p = bs[e];
    int dl = (int)((uint)p >> 17);
    int s = p & 0x1FFFF;
    atomicAdd(&cnt2[chunk8(s) * BNODES + dl], 1);
  }
  __syncthreads();
  if (tid == 0) {
    int run = 0;
    for (int j = 0; j < NCHUNK * BNODES; ++j) { excl2[j] = run; run += cnt2[j]; }
  }
  __syncthreads();
  for (int j = tid; j < nn; j += 256) {
    int deg = 0;
#pragma unroll
    for (int c = 0; c < NCHUNK; ++c) {
      int bin = c * BNODES + j;
      int st = bb + excl2[bin];
      int ln = cnt2[bin];
      rcp[(size_t)(nb0 + j) * 8 + c] = (st << 8) | ln;
      deg += ln;
    }
    dinv[nb0 + j] = rsqrtf((float)(deg + 1));
  }
  __syncthreads();
  for (int j = tid; j < NCHUNK * BNODES; j += 256) cnt2[j] = 0;  // cursors
  __syncthreads();
  for (int e = tid; e < sz; e += 256) {
    int p = bs[e];
    int dl = (int)((uint)p >> 17);
    int s = p & 0x1FFFF;
    int bin = chunk8(s) * BNODES + dl;
    int pos = atomicAdd(&cnt2[bin], 1);
    csr_src[bb + excl2[bin] + pos] = s;
  }
}

// ---- GEMM: C[M][N](bf16) = (X[M][128] @ W[128][N]) * dinv[row]; X fp32 or bf16 ----
template <int N, bool INBF>
__global__ __launch_bounds__(512) void gemm_kernel(const void* __restrict__ Xv,
                                                   const float* __restrict__ W,
                                                   const float* __restrict__ dinv,
                                                   ushort* __restrict__ C, int M) {
  constexpr int BM = 128, BN = 64, BK = 32, K = 128;
  __shared__ float XsT[BK][BM + 4];
  __shared__ float Ws[BK][BN];
  int tid = threadIdx.x;
  int row0 = blockIdx.x * BM;
  int col0 = blockIdx.y * BN;
  int tx = tid & 15;
  int ty = tid >> 4;

  float acc[4][4];
#pragma unroll
  for (int i = 0; i < 4; ++i)
#pragma unroll
    for (int j = 0; j < 4; ++j) acc[i][j] = 0.f;

  for (int k0 = 0; k0 < K; k0 += BK) {
    {
      int r = tid >> 4;
      int c4 = (tid & 15) * 4;
      *(float4*)&Ws[r][c4] = *(const float4*)&W[(size_t)(k0 + r) * N + col0 + c4];
    }
    if (INBF) {
      const ushort* Xb = (const ushort*)Xv;
      int r = tid >> 2;
      int c0 = (tid & 3) * 8;
      uint4 v = make_uint4(0, 0, 0, 0);
      if (row0 + r < M) v = *(const uint4*)&Xb[(size_t)(row0 + r) * K + k0 + c0];
      uint u[4] = {v.x, v.y, v.z, v.w};
#pragma unroll
      for (int j = 0; j < 4; ++j) {
        XsT[c0 + 2 * j][r]     = __uint_as_float(u[j] << 16);
        XsT[c0 + 2 * j + 1][r] = __uint_as_float(u[j] & 0xffff0000u);
      }
    } else {
      const float* Xf = (const float*)Xv;
#pragma unroll
      for (int i = 0; i < 2; ++i) {
        int idx = tid + i * 512;
        int r = idx >> 3;
        int c = (idx & 7) * 4;
        float4 v = make_float4(0.f, 0.f, 0.f, 0.f);
        if (row0 + r < M) v = *(const float4*)&Xf[(size_t)(row0 + r) * K + k0 + c];
        XsT[c + 0][r] = v.x;
        XsT[c + 1][r] = v.y;
        XsT[c + 2][r] = v.z;
        XsT[c + 3][r] = v.w;
      }
    }
    __syncthreads();

#pragma unroll
    for (int kk = 0; kk < BK; ++kk) {
      float4 a = *(float4*)&XsT[kk][ty * 4];
      float4 b = *(float4*)&Ws[kk][tx * 4];
      float av[4] = {a.x, a.y, a.z, a.w};
      float bv[4] = {b.x, b.y, b.z, b.w};
#pragma unroll
      for (int i = 0; i < 4; ++i)
#pragma unroll
        for (int j = 0; j < 4; ++j) acc[i][j] = fmaf(av[i], bv[j], acc[i][j]);
    }
    __syncthreads();
  }

#pragma unroll
  for (int i = 0; i < 4; ++i) {
    int row = row0 + ty * 4 + i;
    if (row < M) {
      float s = dinv[row];
      uint2 st;
      st.x = packbf(acc[i][0] * s, acc[i][1] * s);
      st.y = packbf(acc[i][2] * s, acc[i][3] * s);
      *(uint2*)&C[(size_t)row * N + col0 + tx * 4] = st;
    }
  }
}

// ---- chunk-synchronized persistent aggregation, high-occupancy + 4-wide MLP ----
// MODE 0: H bf16 [n,128] + relu.  MODE 1: H fp32 [n,64] + fused out-linear.
template <int LPN, int ROUNDS, int MODE, bool COOP>
__global__ __launch_bounds__(256, 4) void agg_chunked_kernel(
    const uint4* __restrict__ Tq, const int* __restrict__ rcp,
    const int* __restrict__ csr_src, const float* __restrict__ dinv,
    const float* __restrict__ bias, void* __restrict__ Hv,
    const float* __restrict__ Wout, const float* __restrict__ bout,
    float* __restrict__ Out, int n) {
  constexpr int SPB = 256 / LPN;
  const int SLOTS = AGG_BLOCKS * SPB;
  int lane = threadIdx.x & (LPN - 1);
  int slot0 = blockIdx.x * SPB + (int)(threadIdx.x / LPN);

  float acc[ROUNDS][8];
#pragma unroll
  for (int r = 0; r < ROUNDS; ++r)
#pragma unroll
    for (int j = 0; j < 8; ++j) acc[r][j] = 0.f;

  for (int c = 0; c < NCHUNK; ++c) {
    // prefetch all segment descriptors for this chunk (independent loads)
    int segv[ROUNDS];
#pragma unroll
    for (int r = 0; r < ROUNDS; ++r) {
      int node = slot0 + r * SLOTS;
      segv[r] = (node < n) ? rcp[(size_t)node * 8 + c] : 0;
    }
#pragma unroll
    for (int r = 0; r < ROUNDS; ++r) {
      int node = slot0 + r * SLOTS;
      if (node >= n) continue;
      int lo = segv[r] >> 8;
      int hi = lo + (segv[r] & 255);
      if (chunk8(node) == c) addq(Tq[(size_t)node * LPN + lane], acc[r]);
      int e = lo;
      for (; e + 4 <= hi; e += 4) {
        int s0 = csr_src[e], s1 = csr_src[e + 1];
        int s2 = csr_src[e + 2], s3 = csr_src[e + 3];
        uint4 q0 = Tq[(size_t)s0 * LPN + lane];
        uint4 q1 = Tq[(size_t)s1 * LPN + lane];
        uint4 q2 = Tq[(size_t)s2 * LPN + lane];
        uint4 q3 = Tq[(size_t)s3 * LPN + lane];
        addq(q0, acc[r]); addq(q1, acc[r]); addq(q2, acc[r]); addq(q3, acc[r]);
      }
      if (e + 2 <= hi) {
        int s0 = csr_src[e], s1 = csr_src[e + 1];
        uint4 q0 = Tq[(size_t)s0 * LPN + lane];
        uint4 q1 = Tq[(size_t)s1 * LPN + lane];
        addq(q0, acc[r]); addq(q1, acc[r]);
        e += 2;
      }
      if (e < hi) addq(Tq[(size_t)csr_src[e] * LPN + lane], acc[r]);
    }
    if (COOP) {
      if (c + 1 < NCHUNK) cg::this_grid().sync();
    }
  }

#pragma unroll
  for (int r = 0; r < ROUNDS; ++r) {
    int node = slot0 + r * SLOTS;
    if (node >= n) continue;
    float dn = dinv[node];
    float4 bv0 = *(const float4*)&bias[lane * 8];
    float4 bv1 = *(const float4*)&bias[lane * 8 + 4];
    float bb[8] = {bv0.x, bv0.y, bv0.z, bv0.w, bv1.x, bv1.y, bv1.z, bv1.w};
    float h[8];
#pragma unroll
    for (int j = 0; j < 8; ++j) h[j] = fmaf(dn, acc[r][j], bb[j]);
    if (MODE == 0) {
#pragma unroll
      for (int j = 0; j < 8; ++j) h[j] = fmaxf(h[j], 0.f);
      ushort* Hb = (ushort*)Hv;
      uint4 st;
      st.x = packbf(h[0], h[1]);
      st.y = packbf(h[2], h[3]);
      st.z = packbf(h[4], h[5]);
      st.w = packbf(h[6], h[7]);
      *(uint4*)&Hb[(size_t)node * 128 + lane * 8] = st;
    } else {
      float* Hf = (float*)Hv;
      float* Hrow = &Hf[(size_t)node * 64 + lane * 8];
      *(float4*)&Hrow[0] = make_float4(h[0], h[1], h[2], h[3]);
      *(float4*)&Hrow[4] = make_float4(h[4], h[5], h[6], h[7]);
      int k0 = 8 * lane;
      float p0 = 0.f, p1 = 0.f;
#pragma unroll
      for (int j = 0; j < 8; ++j) {
        p0 = fmaf(h[j], Wout[(k0 + j) * 2 + 0], p0);
        p1 = fmaf(h[j], Wout[(k0 + j) * 2 + 1], p1);
      }
#pragma unroll
      for (int off = 4; off >= 1; off >>= 1) {
        p0 += __shfl_xor(p0, off, 8);
        p1 += __shfl_xor(p1, off, 8);
      }
      if (lane == 0) {
        Out[(size_t)node * 2 + 0] = p0 + bout[0];
        Out[(size_t)node * 2 + 1] = p1 + bout[1];
      }
    }
  }
}

// launch helper: try cooperative, fall back to plain launch of COOP=false variant
template <int LPN, int ROUNDS, int MODE>
static void launch_agg(const uint4* Tq, const int* rcp, const int* csr_src,
                       const float* dinv, const float* bias, void* Hv,
                       const float* Wout, const float* bout, float* Out, int n,
                       hipStream_t stream) {
  const uint4* a0 = Tq; const int* a1 = rcp; const int* a2 = csr_src;
  const float* a3 = dinv; const float* a4 = bias; void* a5 = Hv;
  const float* a6 = Wout; const float* a7 = bout; float* a8 = Out; int a9 = n;
  void* args[] = {&a0, &a1, &a2, &a3, &a4, &a5, &a6, &a7, &a8, &a9};
  hipError_t err = hipLaunchCooperativeKernel(
      reinterpret_cast<void*>(agg_chunked_kernel<LPN, ROUNDS, MODE, true>),
      dim3(AGG_BLOCKS), dim3(256), args, 0, stream);
  if (err != hipSuccess) {
    (void)hipGetLastError();  // clear sticky error
    agg_chunked_kernel<LPN, ROUNDS, MODE, false><<<AGG_BLOCKS, 256, 0, stream>>>(
        Tq, rcp, csr_src, dinv, bias, Hv, Wout, bout, Out, n);
  }
}

extern "C" void kernel_launch(void* const* d_in, const int* in_sizes, int n_in,
                              void* d_out, int out_size, void* d_ws, size_t ws_size,
                              hipStream_t stream) {
  const float* x    = (const float*)d_in[0];
  const int*   ei   = (const int*)d_in[1];
  const float* W1   = (const float*)d_in[2];
  const float* b1   = (const float*)d_in[3];
  const float* W2   = (const float*)d_in[4];
  const float* b2   = (const float*)d_in[5];
  const float* W3   = (const float*)d_in[6];
  const float* b3   = (const float*)d_in[7];
  const float* Wout = (const float*)d_in[8];
  const float* bout = (const float*)d_in[9];

  const int n = NN, E = NE;
  const int* srcp = ei;
  const int* dstp = ei + E;

  char* ws = (char*)d_ws;
  int*    cntmat  = (int*)(ws + 0);            // 1,045,504 B
  int*    btotal  = (int*)(ws + 1045504);      // 4 KB
  int*    bbase   = (int*)(ws + 1049600);      // 4 KB
  int*    offmat  = (int*)(ws + 1053696);      // 1,045,504 B
  int*    rcp     = (int*)(ws + 2099200);      // 3.2 MB
  float*  dinv    = (float*)(ws + 5299200);    // 400 KB
  int*    csr_src = (int*)(ws + 5699216);      // 12.8 MB
  ushort* bufT    = (ushort*)(ws + 18499216);  // 25.6 MB bf16 [n,128]
  int*    store   = (int*)(ws + 18499216);     // 12.8 MB, aliases bufT (dead before gemm1)
  ushort* bufHb   = (ushort*)(ws + 44099216);  // 25.6 MB bf16 [n,128]

  float* outp = (float*)d_out;
  float* hemb = (float*)d_out + 2 * n;

  // ---- graph build ----
  pcount_kernel<<<NBLK, 256, 0, stream>>>(dstp, cntmat);
  rowsum_kernel<<<NB, 256, 0, stream>>>(cntmat, btotal);
  bucket_scan_kernel<<<1, 1024, 0, stream>>>(btotal, bbase);
  offsets_kernel<<<NB, 256, 0, stream>>>(cntmat, bbase, offmat);
  pscatter_kernel<<<NBLK, 256, 0, stream>>>(srcp, dstp, offmat, store);
  build_kernel<<<NB, 256, 0, stream>>>(btotal, bbase, store, rcp, dinv, csr_src);

  // ---- layer 1 ----
  gemm_kernel<128, false><<<dim3((n + 127) / 128, 2), 512, 0, stream>>>(x, W1, dinv, bufT, n);
  launch_agg<16, 7, 0>((const uint4*)bufT, rcp, csr_src, dinv, b1, (void*)bufHb,
                       nullptr, nullptr, nullptr, n, stream);

  // ---- layer 2 ----
  gemm_kernel<128, true><<<dim3((n + 127) / 128, 2), 512, 0, stream>>>(bufHb, W2, dinv, bufT, n);
  launch_agg<16, 7, 0>((const uint4*)bufT, rcp, csr_src, dinv, b2, (void*)bufHb,
                       nullptr, nullptr, nullptr, n, stream);

  // ---- layer 3 + fused output linear ----
  gemm_kernel<64, true><<<dim3((n + 127) / 128, 1), 512, 0, stream>>>(bufHb, W3, dinv, bufT, n);
  launch_agg<8, 4, 1>((const uint4*)bufT, rcp, csr_src, dinv, b3, (void*)hemb,
                      Wout, bout, outp, n, stream);
}

// Round 12
// 545.718 us; speedup vs baseline: 5.8274x; 5.8274x over previous
//
#include <hip/hip_runtime.h>

#define NN 100000
#define NE 3200000
#define NB 1021        // buckets
#define BNODES 98      // nodes per bucket (98*1021 >= NN)
#define NBLK 256       // partition blocks
#define CH 12500       // edges per partition block (NBLK*CH == NE)

typedef unsigned int uint;
typedef __attribute__((ext_vector_type(8))) short short8v;
typedef __attribute__((ext_vector_type(4))) float float4v;

// ---- bf16 helpers (RTNE) ----
__device__ inline uint bfr(float f) {
  uint u = __float_as_uint(f);
  return (u + 0x7fffu + ((u >> 16) & 1u)) >> 16;
}
__device__ inline uint packbf(float a, float b) { return bfr(a) | (bfr(b) << 16); }
__device__ inline void addq(uint4 q, float* a) {
  uint u[4] = {q.x, q.y, q.z, q.w};
#pragma unroll
  for (int j = 0; j < 4; ++j) {
    a[2 * j]     += __uint_as_float(u[j] << 16);
    a[2 * j + 1] += __uint_as_float(u[j] & 0xffff0000u);
  }
}

// ---------------- P1: per-block bucket histogram ----------------
__global__ __launch_bounds__(256) void pcount_kernel(const int* __restrict__ dst,
                                                     int* __restrict__ cntmat) {
  __shared__ int cnt[NB];
  int bk = blockIdx.x, tid = threadIdx.x;
  for (int j = tid; j < NB; j += 256) cnt[j] = 0;
  __syncthreads();
  int base = bk * CH;
  for (int i = base + tid * 4; i < base + CH; i += 1024) {
    int4 d4 = *(const int4*)&dst[i];
    atomicAdd(&cnt[(uint)d4.x / (uint)BNODES], 1);
    atomicAdd(&cnt[(uint)d4.y / (uint)BNODES], 1);
    atomicAdd(&cnt[(uint)d4.z / (uint)BNODES], 1);
    atomicAdd(&cnt[(uint)d4.w / (uint)BNODES], 1);
  }
  __syncthreads();
  for (int j = tid; j < NB; j += 256) cntmat[(size_t)j * NBLK + bk] = cnt[j];
}

// ---------------- P2a: bucket totals ----------------
__global__ __launch_bounds__(256) void rowsum_kernel(const int* __restrict__ cntmat,
                                                     int* __restrict__ btotal) {
  int b = blockIdx.x, t = threadIdx.x;
  int v = cntmat[(size_t)b * NBLK + t];
#pragma unroll
  for (int off = 32; off >= 1; off >>= 1) v += __shfl_xor(v, off, 64);
  __shared__ int ws[4];
  if ((t & 63) == 0) ws[t >> 6] = v;
  __syncthreads();
  if (t == 0) btotal[b] = ws[0] + ws[1] + ws[2] + ws[3];
}

// ---------------- P2b: scan bucket totals -> bases ----------------
__global__ __launch_bounds__(1024) void bucket_scan_kernel(const int* __restrict__ btotal,
                                                           int* __restrict__ bbase,
                                                           int* __restrict__ row_ptr) {
  __shared__ int sh[1024];
  int i = threadIdx.x;
  int v = (i < NB) ? btotal[i] : 0;
  sh[i] = v;
  __syncthreads();
  for (int off = 1; off < 1024; off <<= 1) {
    int t = (i >= off) ? sh[i - off] : 0;
    __syncthreads();
    sh[i] += t;
    __syncthreads();
  }
  if (i < NB) bbase[i] = sh[i] - v;
  if (i == 0) row_ptr[NN] = NE;
}

// ---------------- P2c: per-(bucket,block) offsets ----------------
__global__ __launch_bounds__(256) void offsets_kernel(const int* __restrict__ cntmat,
                                                      const int* __restrict__ bbase,
                                                      int* __restrict__ offmat) {
  __shared__ int sh[256];
  int b = blockIdx.x, t = threadIdx.x;
  int v = cntmat[(size_t)b * NBLK + t];
  sh[t] = v;
  __syncthreads();
  for (int off = 1; off < 256; off <<= 1) {
    int u = (t >= off) ? sh[t - off] : 0;
    __syncthreads();
    sh[t] += u;
    __syncthreads();
  }
  offmat[(size_t)b * NBLK + t] = bbase[b] + sh[t] - v;
}

// ---------------- P3: scatter into bucket-contiguous store (packed 4B) ----------------
__global__ __launch_bounds__(256) void pscatter_kernel(const int* __restrict__ src,
                                                       const int* __restrict__ dst,
                                                       const int* __restrict__ offmat,
                                                       int* __restrict__ store) {
  __shared__ int lcur[NB];
  int bk = blockIdx.x, tid = threadIdx.x;
  for (int j = tid; j < NB; j += 256) lcur[j] = offmat[(size_t)j * NBLK + bk];
  __syncthreads();
  int base = bk * CH;
  for (int i = base + tid * 4; i < base + CH; i += 1024) {
    int4 d4 = *(const int4*)&dst[i];
    int4 s4 = *(const int4*)&src[i];
    int dd[4] = {d4.x, d4.y, d4.z, d4.w};
    int ss[4] = {s4.x, s4.y, s4.z, s4.w};
#pragma unroll
    for (int j = 0; j < 4; ++j) {
      uint b = (uint)dd[j] / (uint)BNODES;
      int dl = dd[j] - (int)(b * BNODES);
      int pos = atomicAdd(&lcur[b], 1);
      store[pos] = ss[j] | (dl << 17);
    }
  }
}

// ---------------- P4: per-bucket CSR build + row_ptr + dinv ----------------
__global__ __launch_bounds__(256) void build_kernel(const int* __restrict__ btotal,
                                                    const int* __restrict__ bbase,
                                                    const int* __restrict__ store,
                                                    int* __restrict__ row_ptr,
                                                    float* __restrict__ dinv,
                                                    int* __restrict__ csr_src) {
  __shared__ int cnt[BNODES];
  __shared__ int excl[BNODES];
  int b = blockIdx.x, tid = threadIdx.x;
  int nb0 = b * BNODES;
  int nn = min(BNODES, NN - nb0);
  for (int j = tid; j < nn; j += 256) cnt[j] = 0;
  __syncthreads();
  int sz = btotal[b], bb = bbase[b];
  const int* bs = store + bb;
  for (int e = tid; e < sz; e += 256) atomicAdd(&cnt[(uint)bs[e] >> 17], 1);
  __syncthreads();
  if (tid == 0) {
    int run = 0;
    for (int j = 0; j < nn; ++j) { excl[j] = run; run += cnt[j]; }
  }
  __syncthreads();
  for (int j = tid; j < nn; j += 256) {
    row_ptr[nb0 + j] = bb + excl[j];
    dinv[nb0 + j] = rsqrtf((float)(cnt[j] + 1));
  }
  __syncthreads();
  for (int j = tid; j < nn; j += 256) cnt[j] = 0;  // reuse as cursor
  __syncthreads();
  for (int e = tid; e < sz; e += 256) {
    int p = bs[e];
    int dl = (int)((uint)p >> 17);
    int pos = atomicAdd(&cnt[dl], 1);
    csr_src[bb + excl[dl] + pos] = p & 0x1FFFF;
  }
}

// ---------------- W -> bf16 transposed: WT[col][k] = bf16(W[k][col]), K=128 ----------------
__global__ __launch_bounds__(256) void wconv_kernel(const float* __restrict__ W,
                                                    ushort* __restrict__ WT, int N) {
  int idx = blockIdx.x * 256 + threadIdx.x;
  if (idx < 128 * N) {
    int col = idx >> 7;
    int k = idx & 127;
    WT[idx] = (ushort)bfr(W[(size_t)k * N + col]);
  }
}

// ---------------- MFMA GEMM: C[M][N](bf16) = (X[M][128] @ W) * dinv[row] ----------------
// X fp32 (INBF=false) or bf16 (true); W pre-converted bf16 WT[N][128].
// 64-row tile, 4 waves; 16x16x32 bf16 MFMA; padded LDS (k-stride 136) kills bank conflicts.
template <int N, bool INBF>
__global__ __launch_bounds__(256) void gemm_mfma_kernel(const void* __restrict__ Xv,
                                                        const ushort* __restrict__ WT,
                                                        const float* __restrict__ dinv,
                                                        ushort* __restrict__ C, int M) {
  constexpr int K = 128;
  constexpr int LDK = K + 8;
  __shared__ ushort Xs[64 * LDK];
  __shared__ ushort Ws[N * LDK];
  int tid = threadIdx.x;
  int row0 = blockIdx.x * 64;

  // stage X tile (convert fp32->bf16 if needed)
#pragma unroll
  for (int i = 0; i < 4; ++i) {
    int idx = (tid + i * 256) * 8;  // 0..8191
    int r = idx >> 7, c = idx & 127;
    uint4 v = make_uint4(0, 0, 0, 0);
    if (row0 + r < M) {
      if (INBF) {
        v = *(const uint4*)((const ushort*)Xv + (size_t)(row0 + r) * K + c);
      } else {
        const float* Xf = (const float*)Xv + (size_t)(row0 + r) * K + c;
        float4 f0 = *(const float4*)Xf;
        float4 f1 = *(const float4*)(Xf + 4);
        v.x = packbf(f0.x, f0.y); v.y = packbf(f0.z, f0.w);
        v.z = packbf(f1.x, f1.y); v.w = packbf(f1.z, f1.w);
      }
    }
    *(uint4*)&Xs[r * LDK + c] = v;
  }
  // stage W (already bf16, transposed [col][k])
#pragma unroll
  for (int i = 0; i < N * K / 2048; ++i) {
    int idx = (tid + i * 256) * 8;
    int col = idx >> 7, k = idx & 127;
    *(uint4*)&Ws[col * LDK + k] = *(const uint4*)&WT[col * K + k];
  }
  __syncthreads();

  int w = tid >> 6, lane = tid & 63;
  int l15 = lane & 15, lhi = lane >> 4;
  constexpr int NF = N / 16;
  float4v acc[NF];
#pragma unroll
  for (int f = 0; f < NF; ++f) acc[f] = (float4v)(0.f);

  const ushort* xbase = &Xs[(w * 16 + l15) * LDK + lhi * 8];
#pragma unroll
  for (int s = 0; s < 4; ++s) {  // K steps of 32
    short8v a = *(const short8v*)(xbase + s * 32);
#pragma unroll
    for (int f = 0; f < NF; ++f) {
      short8v b = *(const short8v*)&Ws[(f * 16 + l15) * LDK + s * 32 + lhi * 8];
      acc[f] = __builtin_amdgcn_mfma_f32_16x16x32_bf16(a, b, acc[f], 0, 0, 0);
    }
  }

  // C/D layout: col = f*16 + (lane&15), row = w*16 + (lane>>4)*4 + j
  int rbase = row0 + w * 16 + lhi * 4;
  float dv[4];
#pragma unroll
  for (int j = 0; j < 4; ++j) dv[j] = (rbase + j < M) ? dinv[rbase + j] : 0.f;
#pragma unroll
  for (int f = 0; f < NF; ++f) {
#pragma unroll
    for (int j = 0; j < 4; ++j) {
      int row = rbase + j;
      if (row < M) C[(size_t)row * N + f * 16 + l15] = (ushort)bfr(acc[f][j] * dv[j]);
    }
  }
}

// ---- 128-ch bf16-gather aggregation: H bf16 = relu(dn*(sum bf16 Tp) + b) ----
// 16 lanes/node, 8 channels (uint4, 16B) per lane. 256B contiguous per gathered row.
__global__ __launch_bounds__(256) void agg_bf16_kernel(const uint4* __restrict__ Tq,
                                                       const int* __restrict__ row_ptr,
                                                       const int* __restrict__ csr_src,
                                                       const float* __restrict__ dinv,
                                                       const float* __restrict__ bias,
                                                       ushort* __restrict__ H, int n) {
  int t = blockIdx.x * 256 + threadIdx.x;
  int node = t >> 4;
  int lane = t & 15;
  if (node >= n) return;

  float dn = dinv[node];
  float a0[8], a1[8], a2[8], a3[8];
#pragma unroll
  for (int c = 0; c < 8; ++c) { a0[c] = 0.f; a1[c] = 0.f; a2[c] = 0.f; a3[c] = 0.f; }
  addq(Tq[(size_t)node * 16 + lane], a0);  // self term (prescaled)

  int beg = row_ptr[node], end = row_ptr[node + 1];
  int e = beg;
  int ae = min(end, (beg + 3) & ~3);
  for (; e < ae; ++e) addq(Tq[(size_t)csr_src[e] * 16 + lane], a0);
  for (; e + 4 <= end; e += 4) {
    int4 s4 = *(const int4*)&csr_src[e];
    uint4 q0 = Tq[(size_t)s4.x * 16 + lane];
    uint4 q1 = Tq[(size_t)s4.y * 16 + lane];
    uint4 q2 = Tq[(size_t)s4.z * 16 + lane];
    uint4 q3 = Tq[(size_t)s4.w * 16 + lane];
    addq(q0, a0); addq(q1, a1); addq(q2, a2); addq(q3, a3);
  }
  for (; e < end; ++e) addq(Tq[(size_t)csr_src[e] * 16 + lane], a0);

  float4 bv0 = *(const float4*)&bias[lane * 8];
  float4 bv1 = *(const float4*)&bias[lane * 8 + 4];
  float bb[8] = {bv0.x, bv0.y, bv0.z, bv0.w, bv1.x, bv1.y, bv1.z, bv1.w};
  float h[8];
#pragma unroll
  for (int c = 0; c < 8; ++c) {
    h[c] = fmaf(dn, (a0[c] + a1[c]) + (a2[c] + a3[c]), bb[c]);
    h[c] = fmaxf(h[c], 0.f);
  }
  uint4 st;
  st.x = packbf(h[0], h[1]);
  st.y = packbf(h[2], h[3]);
  st.z = packbf(h[4], h[5]);
  st.w = packbf(h[6], h[7]);
  *(uint4*)&H[(size_t)node * 128 + lane * 8] = st;
}

// ---- 64-ch bf16-gather aggregation + fused final linear (layer 3) ----
__global__ __launch_bounds__(256) void agg64_kernel(const uint4* __restrict__ Tq,
                                                    const int* __restrict__ row_ptr,
                                                    const int* __restrict__ csr_src,
                                                    const float* __restrict__ dinv,
                                                    const float* __restrict__ bias,
                                                    float* __restrict__ H,
                                                    const float* __restrict__ Wout,
                                                    const float* __restrict__ bout,
                                                    float* __restrict__ Out, int n) {
  int t = blockIdx.x * 256 + threadIdx.x;
  int node = t >> 3;
  int lane = t & 7;
  if (node >= n) return;

  float dn = dinv[node];
  float a0[8], a1[8], a2[8], a3[8];
#pragma unroll
  for (int c = 0; c < 8; ++c) { a0[c] = 0.f; a1[c] = 0.f; a2[c] = 0.f; a3[c] = 0.f; }
  addq(Tq[(size_t)node * 8 + lane], a0);

  int beg = row_ptr[node], end = row_ptr[node + 1];
  int e = beg;
  int ae = min(end, (beg + 3) & ~3);
  for (; e < ae; ++e) addq(Tq[(size_t)csr_src[e] * 8 + lane], a0);
  for (; e + 4 <= end; e += 4) {
    int4 s4 = *(const int4*)&csr_src[e];
    uint4 q0 = Tq[(size_t)s4.x * 8 + lane];
    uint4 q1 = Tq[(size_t)s4.y * 8 + lane];
    uint4 q2 = Tq[(size_t)s4.z * 8 + lane];
    uint4 q3 = Tq[(size_t)s4.w * 8 + lane];
    addq(q0, a0); addq(q1, a1); addq(q2, a2); addq(q3, a3);
  }
  for (; e < end; ++e) addq(Tq[(size_t)csr_src[e] * 8 + lane], a0);

  float4 bv0 = *(const float4*)&bias[lane * 8];
  float4 bv1 = *(const float4*)&bias[lane * 8 + 4];
  float bb[8] = {bv0.x, bv0.y, bv0.z, bv0.w, bv1.x, bv1.y, bv1.z, bv1.w};
  float h[8];
#pragma unroll
  for (int c = 0; c < 8; ++c)
    h[c] = fmaf(dn, (a0[c] + a1[c]) + (a2[c] + a3[c]), bb[c]);

  float* Hrow = &H[(size_t)node * 64 + lane * 8];
  *(float4*)&Hrow[0] = make_float4(h[0], h[1], h[2], h[3]);
  *(float4*)&Hrow[4] = make_float4(h[4], h[5], h[6], h[7]);

  int k0 = 8 * lane;
  float p0 = 0.f, p1 = 0.f;
#pragma unroll
  for (int c = 0; c < 8; ++c) {
    p0 = fmaf(h[c], Wout[(k0 + c) * 2 + 0], p0);
    p1 = fmaf(h[c], Wout[(k0 + c) * 2 + 1], p1);
  }
#pragma unroll
  for (int off = 4; off >= 1; off >>= 1) {
    p0 += __shfl_xor(p0, off, 8);
    p1 += __shfl_xor(p1, off, 8);
  }
  if (lane == 0) {
    Out[(size_t)node * 2 + 0] = p0 + bout[0];
    Out[(size_t)node * 2 + 1] = p1 + bout[1];
  }
}

extern "C" void kernel_launch(void* const* d_in, const int* in_sizes, int n_in,
                              void* d_out, int out_size, void* d_ws, size_t ws_size,
                              hipStream_t stream) {
  const float* x    = (const float*)d_in[0];
  const int*   ei   = (const int*)d_in[1];
  const float* W1   = (const float*)d_in[2];
  const float* b1   = (const float*)d_in[3];
  const float* W2   = (const float*)d_in[4];
  const float* b2   = (const float*)d_in[5];
  const float* W3   = (const float*)d_in[6];
  const float* b3   = (const float*)d_in[7];
  const float* Wout = (const float*)d_in[8];
  const float* bout = (const float*)d_in[9];

  const int n = NN, E = NE;
  const int* srcp = ei;
  const int* dstp = ei + E;

  char* ws = (char*)d_ws;
  int*    cntmat  = (int*)(ws + 0);            // 1,045,504 B
  int*    btotal  = (int*)(ws + 1045504);      // 4 KB
  int*    bbase   = (int*)(ws + 1049600);      // 4 KB
  int*    offmat  = (int*)(ws + 1053696);      // 1,045,504 B
  int*    row_ptr = (int*)(ws + 2099200);      // 400,016 B
  float*  dinv    = (float*)(ws + 2499216);    // 400,000 B
  int*    csr_src = (int*)(ws + 2899216);      // 12.8 MB -> 15,699,216
  ushort* WT1     = (ushort*)(ws + 15699216);  // 32 KB
  ushort* WT2     = (ushort*)(ws + 15731984);  // 32 KB
  ushort* WT3     = (ushort*)(ws + 15764752);  // 16 KB -> 15,781,136
  ushort* bufT    = (ushort*)(ws + 15781136);  // 25.6 MB bf16 [n,128] -> 41,381,136
  ushort* bufHb   = (ushort*)(ws + 41381136);  // 25.6 MB bf16 [n,128]
  int*    store   = (int*)(ws + 41381136);     // 12.8 MB, aliases bufHb (dead before agg1)

  float* outp = (float*)d_out;
  float* hemb = (float*)d_out + 2 * n;

  // ---- graph build (atomic-free radix partition) ----
  pcount_kernel<<<NBLK, 256, 0, stream>>>(dstp, cntmat);
  rowsum_kernel<<<NB, 256, 0, stream>>>(cntmat, btotal);
  bucket_scan_kernel<<<1, 1024, 0, stream>>>(btotal, bbase, row_ptr);
  offsets_kernel<<<NB, 256, 0, stream>>>(cntmat, bbase, offmat);
  pscatter_kernel<<<NBLK, 256, 0, stream>>>(srcp, dstp, offmat, store);
  build_kernel<<<NB, 256, 0, stream>>>(btotal, bbase, store, row_ptr, dinv, csr_src);

  // ---- W -> bf16 transposed ----
  wconv_kernel<<<(128 * 128 + 255) / 256, 256, 0, stream>>>(W1, WT1, 128);
  wconv_kernel<<<(128 * 128 + 255) / 256, 256, 0, stream>>>(W2, WT2, 128);
  wconv_kernel<<<(128 * 64 + 255) / 256, 256, 0, stream>>>(W3, WT3, 64);

  int gemmGrid = (n + 63) / 64;

  // ---- layer 1 ----
  gemm_mfma_kernel<128, false><<<gemmGrid, 256, 0, stream>>>(x, WT1, dinv, bufT, n);
  agg_bf16_kernel<<<(n * 16 + 255) / 256, 256, 0, stream>>>(
      (const uint4*)bufT, row_ptr, csr_src, dinv, b1, bufHb, n);

  // ---- layer 2 ----
  gemm_mfma_kernel<128, true><<<gemmGrid, 256, 0, stream>>>(bufHb, WT2, dinv, bufT, n);
  agg_bf16_kernel<<<(n * 16 + 255) / 256, 256, 0, stream>>>(
      (const uint4*)bufT, row_ptr, csr_src, dinv, b2, bufHb, n);

  // ---- layer 3 (64 ch) + fused final linear ----
  gemm_mfma_kernel<64, true><<<gemmGrid, 256, 0, stream>>>(bufHb, WT3, dinv, bufT, n);
  agg64_kernel<<<(n * 8 + 255) / 256, 256, 0, stream>>>(
      (const uint4*)bufT, row_ptr, csr_src, dinv, b3, hemb, Wout, bout, outp, n);
}

// Round 13
// 502.399 us; speedup vs baseline: 6.3299x; 1.0862x over previous
//
#include <hip/hip_runtime.h>

#define NN 100000
#define NE 3200000
#define NB 1021        // buckets
#define BNODES 98      // nodes per bucket (98*1021 >= NN)
#define NBLK 256       // partition blocks
#define CH 12500       // edges per partition block (NBLK*CH == NE)
#define NCHUNK 8       // src chunks; chunk == XCD via blockIdx&7
#define NPB 400        // nodes per group in aggp
#define NGRP 256       // groups; NGRP*NPB >= NN

typedef unsigned int uint;
typedef __attribute__((ext_vector_type(8))) short short8v;
typedef __attribute__((ext_vector_type(4))) float float4v;

// ---- bf16 helpers (RTNE) ----
__device__ inline uint bfr(float f) {
  uint u = __float_as_uint(f);
  return (u + 0x7fffu + ((u >> 16) & 1u)) >> 16;
}
__device__ inline uint packbf(float a, float b) { return bfr(a) | (bfr(b) << 16); }
__device__ inline void addq(uint4 q, float* a) {
  uint u[4] = {q.x, q.y, q.z, q.w};
#pragma unroll
  for (int j = 0; j < 4; ++j) {
    a[2 * j]     += __uint_as_float(u[j] << 16);
    a[2 * j + 1] += __uint_as_float(u[j] & 0xffff0000u);
  }
}
// chunk = s / 12500 via magic multiply (exact for s < 2^17)
__device__ inline int chunk8(int s) {
  return (int)(((unsigned long long)(uint)s * 343598ull) >> 32);
}

// ---------------- P1: per-block bucket histogram ----------------
__global__ __launch_bounds__(256) void pcount_kernel(const int* __restrict__ dst,
                                                     int* __restrict__ cntmat) {
  __shared__ int cnt[NB];
  int bk = blockIdx.x, tid = threadIdx.x;
  for (int j = tid; j < NB; j += 256) cnt[j] = 0;
  __syncthreads();
  int base = bk * CH;
  for (int i = base + tid * 4; i < base + CH; i += 1024) {
    int4 d4 = *(const int4*)&dst[i];
    atomicAdd(&cnt[(uint)d4.x / (uint)BNODES], 1);
    atomicAdd(&cnt[(uint)d4.y / (uint)BNODES], 1);
    atomicAdd(&cnt[(uint)d4.z / (uint)BNODES], 1);
    atomicAdd(&cnt[(uint)d4.w / (uint)BNODES], 1);
  }
  __syncthreads();
  for (int j = tid; j < NB; j += 256) cntmat[(size_t)j * NBLK + bk] = cnt[j];
}

// ---------------- P2a: bucket totals ----------------
__global__ __launch_bounds__(256) void rowsum_kernel(const int* __restrict__ cntmat,
                                                     int* __restrict__ btotal) {
  int b = blockIdx.x, t = threadIdx.x;
  int v = cntmat[(size_t)b * NBLK + t];
#pragma unroll
  for (int off = 32; off >= 1; off >>= 1) v += __shfl_xor(v, off, 64);
  __shared__ int ws[4];
  if ((t & 63) == 0) ws[t >> 6] = v;
  __syncthreads();
  if (t == 0) btotal[b] = ws[0] + ws[1] + ws[2] + ws[3];
}

// ---------------- P2b: scan bucket totals -> bases ----------------
__global__ __launch_bounds__(1024) void bucket_scan_kernel(const int* __restrict__ btotal,
                                                           int* __restrict__ bbase) {
  __shared__ int sh[1024];
  int i = threadIdx.x;
  int v = (i < NB) ? btotal[i] : 0;
  sh[i] = v;
  __syncthreads();
  for (int off = 1; off < 1024; off <<= 1) {
    int t = (i >= off) ? sh[i - off] : 0;
    __syncthreads();
    sh[i] += t;
    __syncthreads();
  }
  if (i < NB) bbase[i] = sh[i] - v;
}

// ---------------- P2c: per-(bucket,block) offsets ----------------
__global__ __launch_bounds__(256) void offsets_kernel(const int* __restrict__ cntmat,
                                                      const int* __restrict__ bbase,
                                                      int* __restrict__ offmat) {
  __shared__ int sh[256];
  int b = blockIdx.x, t = threadIdx.x;
  int v = cntmat[(size_t)b * NBLK + t];
  sh[t] = v;
  __syncthreads();
  for (int off = 1; off < 256; off <<= 1) {
    int u = (t >= off) ? sh[t - off] : 0;
    __syncthreads();
    sh[t] += u;
    __syncthreads();
  }
  offmat[(size_t)b * NBLK + t] = bbase[b] + sh[t] - v;
}

// ---------------- P3: scatter into bucket-contiguous store (packed 4B) ----------------
__global__ __launch_bounds__(256) void pscatter_kernel(const int* __restrict__ src,
                                                       const int* __restrict__ dst,
                                                       const int* __restrict__ offmat,
                                                       int* __restrict__ store) {
  __shared__ int lcur[NB];
  int bk = blockIdx.x, tid = threadIdx.x;
  for (int j = tid; j < NB; j += 256) lcur[j] = offmat[(size_t)j * NBLK + bk];
  __syncthreads();
  int base = bk * CH;
  for (int i = base + tid * 4; i < base + CH; i += 1024) {
    int4 d4 = *(const int4*)&dst[i];
    int4 s4 = *(const int4*)&src[i];
    int dd[4] = {d4.x, d4.y, d4.z, d4.w};
    int ss[4] = {s4.x, s4.y, s4.z, s4.w};
#pragma unroll
    for (int j = 0; j < 4; ++j) {
      uint b = (uint)dd[j] / (uint)BNODES;
      int dl = dd[j] - (int)(b * BNODES);
      int pos = atomicAdd(&lcur[b], 1);
      store[pos] = ss[j] | (dl << 17);
    }
  }
}

// ---------------- P4: per-bucket chunk-major CSR + packed rcp + dinv ----------------
// bin = c*BNODES + dl; rcp[node*8+c] = (abs_start<<8)|len
__global__ __launch_bounds__(256) void build_kernel(const int* __restrict__ btotal,
                                                    const int* __restrict__ bbase,
                                                    const int* __restrict__ store,
                                                    int* __restrict__ rcp,
                                                    float* __restrict__ dinv,
                                                    int* __restrict__ csr_src) {
  __shared__ int cnt2[NCHUNK * BNODES];
  __shared__ int excl2[NCHUNK * BNODES];
  int b = blockIdx.x, tid = threadIdx.x;
  int nb0 = b * BNODES;
  int nn = min(BNODES, NN - nb0);
  for (int j = tid; j < NCHUNK * BNODES; j += 256) cnt2[j] = 0;
  __syncthreads();
  int sz = btotal[b], bb = bbase[b];
  const int* bs = store + bb;
  for (int e = tid; e < sz; e += 256) {
    int p = bs[e];
    int dl = (int)((uint)p >> 17);
    int s = p & 0x1FFFF;
    atomicAdd(&cnt2[chunk8(s) * BNODES + dl], 1);
  }
  __syncthreads();
  if (tid == 0) {
    int run = 0;
    for (int j = 0; j < NCHUNK * BNODES; ++j) { excl2[j] = run; run += cnt2[j]; }
  }
  __syncthreads();
  for (int j = tid; j < nn; j += 256) {
    int deg = 0;
#pragma unroll
    for (int c = 0; c < NCHUNK; ++c) {
      int bin = c * BNODES + j;
      rcp[(size_t)(nb0 + j) * 8 + c] = ((bb + excl2[bin]) << 8) | cnt2[bin];
      deg += cnt2[bin];
    }
    dinv[nb0 + j] = rsqrtf((float)(deg + 1));
  }
  __syncthreads();
  for (int j = tid; j < NCHUNK * BNODES; j += 256) cnt2[j] = 0;  // cursors
  __syncthreads();
  for (int e = tid; e < sz; e += 256) {
    int p = bs[e];
    int dl = (int)((uint)p >> 17);
    int s = p & 0x1FFFF;
    int bin = chunk8(s) * BNODES + dl;
    int pos = atomicAdd(&cnt2[bin], 1);
    csr_src[bb + excl2[bin] + pos] = s;
  }
}

// ---------------- W -> bf16 transposed: WT[col][k] = bf16(W[k][col]), K=128 ----------------
__global__ __launch_bounds__(256) void wconv_kernel(const float* __restrict__ W,
                                                    ushort* __restrict__ WT, int N) {
  int idx = blockIdx.x * 256 + threadIdx.x;
  if (idx < 128 * N) {
    int col = idx >> 7;
    int k = idx & 127;
    WT[idx] = (ushort)bfr(W[(size_t)k * N + col]);
  }
}

// ---------------- MFMA GEMM (layer 1): C[M][N](bf16) = (X@W)*dinv ----------------
template <int N, bool INBF>
__global__ __launch_bounds__(256) void gemm_mfma_kernel(const void* __restrict__ Xv,
                                                        const ushort* __restrict__ WT,
                                                        const float* __restrict__ dinv,
                                                        ushort* __restrict__ C, int M) {
  constexpr int K = 128;
  constexpr int LDK = K + 8;
  __shared__ ushort Xs[64 * LDK];
  __shared__ ushort Ws[N * LDK];
  int tid = threadIdx.x;
  int row0 = blockIdx.x * 64;

#pragma unroll
  for (int i = 0; i < 4; ++i) {
    int idx = (tid + i * 256) * 8;
    int r = idx >> 7, c = idx & 127;
    uint4 v = make_uint4(0, 0, 0, 0);
    if (row0 + r < M) {
      if (INBF) {
        v = *(const uint4*)((const ushort*)Xv + (size_t)(row0 + r) * K + c);
      } else {
        const float* Xf = (const float*)Xv + (size_t)(row0 + r) * K + c;
        float4 f0 = *(const float4*)Xf;
        float4 f1 = *(const float4*)(Xf + 4);
        v.x = packbf(f0.x, f0.y); v.y = packbf(f0.z, f0.w);
        v.z = packbf(f1.x, f1.y); v.w = packbf(f1.z, f1.w);
      }
    }
    *(uint4*)&Xs[r * LDK + c] = v;
  }
#pragma unroll
  for (int i = 0; i < N * K / 2048; ++i) {
    int idx = (tid + i * 256) * 8;
    int col = idx >> 7, k = idx & 127;
    *(uint4*)&Ws[col * LDK + k] = *(const uint4*)&WT[col * K + k];
  }
  __syncthreads();

  int w = tid >> 6, lane = tid & 63;
  int l15 = lane & 15, lhi = lane >> 4;
  constexpr int NF = N / 16;
  float4v acc[NF];
#pragma unroll
  for (int f = 0; f < NF; ++f) acc[f] = (float4v)(0.f);

  const ushort* xbase = &Xs[(w * 16 + l15) * LDK + lhi * 8];
#pragma unroll
  for (int s = 0; s < 4; ++s) {
    short8v a = *(const short8v*)(xbase + s * 32);
#pragma unroll
    for (int f = 0; f < NF; ++f) {
      short8v b = *(const short8v*)&Ws[(f * 16 + l15) * LDK + s * 32 + lhi * 8];
      acc[f] = __builtin_amdgcn_mfma_f32_16x16x32_bf16(a, b, acc[f], 0, 0, 0);
    }
  }

  int rbase = row0 + w * 16 + lhi * 4;
  float dv[4];
#pragma unroll
  for (int j = 0; j < 4; ++j) dv[j] = (rbase + j < M) ? dinv[rbase + j] : 0.f;
#pragma unroll
  for (int f = 0; f < NF; ++f) {
#pragma unroll
    for (int j = 0; j < 4; ++j) {
      int row = rbase + j;
      if (row < M) C[(size_t)row * N + f * 16 + l15] = (ushort)bfr(acc[f][j] * dv[j]);
    }
  }
}

// ---- XCD-partitioned partial aggregation: chunk = blockIdx&7 (== XCD under RR dispatch) ----
// P_c[node] = sum of Tp rows whose src is in chunk c (+ self if chunk8(node)==c). bf16 out.
template <int LPN>
__global__ __launch_bounds__(256) void aggp_kernel(const uint4* __restrict__ Tq,
                                                   const int* __restrict__ rcp,
                                                   const int* __restrict__ csr_src,
                                                   ushort* __restrict__ P, int n) {
  int c = blockIdx.x & 7;
  int g = blockIdx.x >> 3;
  constexpr int SPB = 256 / LPN;
  int lane = threadIdx.x & (LPN - 1);
  int slot = threadIdx.x / LPN;
  uint4* Pq = (uint4*)P + (size_t)c * n * LPN;
  constexpr int ITERS = (NPB + SPB - 1) / SPB;
  for (int it = 0; it < ITERS; ++it) {
    int off = it * SPB + slot;
    if (off >= NPB) break;
    int node = g * NPB + off;
    if (node >= n) break;
    int v = rcp[(size_t)node * 8 + c];
    int lo = v >> 8, hi = lo + (v & 255);
    float a[8];
#pragma unroll
    for (int j = 0; j < 8; ++j) a[j] = 0.f;
    if (chunk8(node) == c) addq(Tq[(size_t)node * LPN + lane], a);
    int e = lo;
    for (; e + 4 <= hi; e += 4) {
      int s0 = csr_src[e], s1 = csr_src[e + 1];
      int s2 = csr_src[e + 2], s3 = csr_src[e + 3];
      uint4 q0 = Tq[(size_t)s0 * LPN + lane];
      uint4 q1 = Tq[(size_t)s1 * LPN + lane];
      uint4 q2 = Tq[(size_t)s2 * LPN + lane];
      uint4 q3 = Tq[(size_t)s3 * LPN + lane];
      addq(q0, a); addq(q1, a); addq(q2, a); addq(q3, a);
    }
    for (; e < hi; ++e) addq(Tq[(size_t)csr_src[e] * LPN + lane], a);
    uint4 st;
    st.x = packbf(a[0], a[1]);
    st.y = packbf(a[2], a[3]);
    st.z = packbf(a[4], a[5]);
    st.w = packbf(a[6], a[7]);
    Pq[(size_t)node * LPN + lane] = st;
  }
}

// ---- fused GEMM: h = relu(dn*sum_c P_c + b); C = (h @ W)*dinv, bf16 ----
template <int N>
__global__ __launch_bounds__(256) void gemm_fused_kernel(const ushort* __restrict__ P,
                                                         const ushort* __restrict__ WT,
                                                         const float* __restrict__ dinv,
                                                         const float* __restrict__ bias,
                                                         ushort* __restrict__ C, int M) {
  constexpr int K = 128;
  constexpr int LDK = K + 8;
  __shared__ ushort Xs[64 * LDK];
  __shared__ ushort Ws[N * LDK];
  int tid = threadIdx.x;
  int row0 = blockIdx.x * 64;
  const uint4* Pq = (const uint4*)P;
  size_t ps = (size_t)M * 16;  // uint4 stride per partial

  {
    int l = tid & 15;
    int rb = tid >> 4;
    float4 bv0 = *(const float4*)&bias[l * 8];
    float4 bv1 = *(const float4*)&bias[l * 8 + 4];
    float bb[8] = {bv0.x, bv0.y, bv0.z, bv0.w, bv1.x, bv1.y, bv1.z, bv1.w};
#pragma unroll
    for (int i = 0; i < 4; ++i) {
      int r = rb + i * 16;
      int row = row0 + r;
      uint4 st = make_uint4(0, 0, 0, 0);
      if (row < M) {
        float a[8];
#pragma unroll
        for (int j = 0; j < 8; ++j) a[j] = 0.f;
#pragma unroll
        for (int c = 0; c < 8; ++c)
          addq(Pq[(size_t)c * ps + (size_t)row * 16 + l], a);
        float dn = dinv[row];
        float h[8];
#pragma unroll
        for (int j = 0; j < 8; ++j) h[j] = fmaxf(fmaf(dn, a[j], bb[j]), 0.f);
        st.x = packbf(h[0], h[1]);
        st.y = packbf(h[2], h[3]);
        st.z = packbf(h[4], h[5]);
        st.w = packbf(h[6], h[7]);
      }
      *(uint4*)&Xs[r * LDK + l * 8] = st;
    }
  }
#pragma unroll
  for (int i = 0; i < N * K / 2048; ++i) {
    int idx = (tid + i * 256) * 8;
    int col = idx >> 7, k = idx & 127;
    *(uint4*)&Ws[col * LDK + k] = *(const uint4*)&WT[col * K + k];
  }
  __syncthreads();

  int w = tid >> 6, lane = tid & 63;
  int l15 = lane & 15, lhi = lane >> 4;
  constexpr int NF = N / 16;
  float4v acc[NF];
#pragma unroll
  for (int f = 0; f < NF; ++f) acc[f] = (float4v)(0.f);

  const ushort* xbase = &Xs[(w * 16 + l15) * LDK + lhi * 8];
#pragma unroll
  for (int s = 0; s < 4; ++s) {
    short8v a = *(const short8v*)(xbase + s * 32);
#pragma unroll
    for (int f = 0; f < NF; ++f) {
      short8v b = *(const short8v*)&Ws[(f * 16 + l15) * LDK + s * 32 + lhi * 8];
      acc[f] = __builtin_amdgcn_mfma_f32_16x16x32_bf16(a, b, acc[f], 0, 0, 0);
    }
  }

  int rbase = row0 + w * 16 + lhi * 4;
  float dv[4];
#pragma unroll
  for (int j = 0; j < 4; ++j) dv[j] = (rbase + j < M) ? dinv[rbase + j] : 0.f;
#pragma unroll
  for (int f = 0; f < NF; ++f) {
#pragma unroll
    for (int j = 0; j < 4; ++j) {
      int row = rbase + j;
      if (row < M) C[(size_t)row * N + f * 16 + l15] = (ushort)bfr(acc[f][j] * dv[j]);
    }
  }
}

// ---- layer-3 reduce: h3 = dn*sum_c P3_c + b3 -> hemb fp32; out = h3@Wout + bout ----
__global__ __launch_bounds__(256) void reduce3_kernel(const ushort* __restrict__ P,
                                                      const float* __restrict__ dinv,
                                                      const float* __restrict__ b3,
                                                      const float* __restrict__ Wout,
                                                      const float* __restrict__ bout,
                                                      float* __restrict__ Hemb,
                                                      float* __restrict__ Out, int n) {
  int t = blockIdx.x * 256 + threadIdx.x;
  int node = t >> 3;
  int lane = t & 7;
  if (node >= n) return;
  const uint4* Pq = (const uint4*)P;
  size_t ps = (size_t)n * 8;
  float a[8];
#pragma unroll
  for (int j = 0; j < 8; ++j) a[j] = 0.f;
#pragma unroll
  for (int c = 0; c < 8; ++c) addq(Pq[(size_t)c * ps + (size_t)node * 8 + lane], a);
  float dn = dinv[node];
  float4 bv0 = *(const float4*)&b3[lane * 8];
  float4 bv1 = *(const float4*)&b3[lane * 8 + 4];
  float bb[8] = {bv0.x, bv0.y, bv0.z, bv0.w, bv1.x, bv1.y, bv1.z, bv1.w};
  float h[8];
#pragma unroll
  for (int j = 0; j < 8; ++j) h[j] = fmaf(dn, a[j], bb[j]);
  float* Hrow = &Hemb[(size_t)node * 64 + lane * 8];
  *(float4*)&Hrow[0] = make_float4(h[0], h[1], h[2], h[3]);
  *(float4*)&Hrow[4] = make_float4(h[4], h[5], h[6], h[7]);
  int k0 = 8 * lane;
  float p0 = 0.f, p1 = 0.f;
#pragma unroll
  for (int j = 0; j < 8; ++j) {
    p0 = fmaf(h[j], Wout[(k0 + j) * 2 + 0], p0);
    p1 = fmaf(h[j], Wout[(k0 + j) * 2 + 1], p1);
  }
#pragma unroll
  for (int off = 4; off >= 1; off >>= 1) {
    p0 += __shfl_xor(p0, off, 8);
    p1 += __shfl_xor(p1, off, 8);
  }
  if (lane == 0) {
    Out[(size_t)node * 2 + 0] = p0 + bout[0];
    Out[(size_t)node * 2 + 1] = p1 + bout[1];
  }
}

// ---- fallback (small ws): direct bf16 gather agg over rcp segments ----
__global__ __launch_bounds__(256) void agg_fb128_kernel(const uint4* __restrict__ Tq,
                                                        const int* __restrict__ rcp,
                                                        const int* __restrict__ csr_src,
                                                        const float* __restrict__ dinv,
                                                        const float* __restrict__ bias,
                                                        ushort* __restrict__ H, int n) {
  int t = blockIdx.x * 256 + threadIdx.x;
  int node = t >> 4;
  int lane = t & 15;
  if (node >= n) return;
  float dn = dinv[node];
  float a0[8], a1[8], a2[8], a3[8];
#pragma unroll
  for (int c = 0; c < 8; ++c) { a0[c] = 0.f; a1[c] = 0.f; a2[c] = 0.f; a3[c] = 0.f; }
  addq(Tq[(size_t)node * 16 + lane], a0);
#pragma unroll
  for (int c = 0; c < 8; ++c) {
    int v = rcp[(size_t)node * 8 + c];
    int lo = v >> 8, hi = lo + (v & 255);
    int e = lo;
    for (; e + 4 <= hi; e += 4) {
      uint4 q0 = Tq[(size_t)csr_src[e] * 16 + lane];
      uint4 q1 = Tq[(size_t)csr_src[e + 1] * 16 + lane];
      uint4 q2 = Tq[(size_t)csr_src[e + 2] * 16 + lane];
      uint4 q3 = Tq[(size_t)csr_src[e + 3] * 16 + lane];
      addq(q0, a0); addq(q1, a1); addq(q2, a2); addq(q3, a3);
    }
    for (; e < hi; ++e) addq(Tq[(size_t)csr_src[e] * 16 + lane], a0);
  }
  float4 bv0 = *(const float4*)&bias[lane * 8];
  float4 bv1 = *(const float4*)&bias[lane * 8 + 4];
  float bb[8] = {bv0.x, bv0.y, bv0.z, bv0.w, bv1.x, bv1.y, bv1.z, bv1.w};
  float h[8];
#pragma unroll
  for (int c = 0; c < 8; ++c) {
    h[c] = fmaf(dn, (a0[c] + a1[c]) + (a2[c] + a3[c]), bb[c]);
    h[c] = fmaxf(h[c], 0.f);
  }
  uint4 st;
  st.x = packbf(h[0], h[1]);
  st.y = packbf(h[2], h[3]);
  st.z = packbf(h[4], h[5]);
  st.w = packbf(h[6], h[7]);
  *(uint4*)&H[(size_t)node * 128 + lane * 8] = st;
}

__global__ __launch_bounds__(256) void agg_fb64_kernel(const uint4* __restrict__ Tq,
                                                       const int* __restrict__ rcp,
                                                       const int* __restrict__ csr_src,
                                                       const float* __restrict__ dinv,
                                                       const float* __restrict__ bias,
                                                       float* __restrict__ H,
                                                       const float* __restrict__ Wout,
                                                       const float* __restrict__ bout,
                                                       float* __restrict__ Out, int n) {
  int t = blockIdx.x * 256 + threadIdx.x;
  int node = t >> 3;
  int lane = t & 7;
  if (node >= n) return;
  float dn = dinv[node];
  float a0[8], a1[8], a2[8], a3[8];
#pragma unroll
  for (int c = 0; c < 8; ++c) { a0[c] = 0.f; a1[c] = 0.f; a2[c] = 0.f; a3[c] = 0.f; }
  addq(Tq[(size_t)node * 8 + lane], a0);
#pragma unroll
  for (int c = 0; c < 8; ++c) {
    int v = rcp[(size_t)node * 8 + c];
    int lo = v >> 8, hi = lo + (v & 255);
    int e = lo;
    for (; e + 4 <= hi; e += 4) {
      uint4 q0 = Tq[(size_t)csr_src[e] * 8 + lane];
      uint4 q1 = Tq[(size_t)csr_src[e + 1] * 8 + lane];
      uint4 q2 = Tq[(size_t)csr_src[e + 2] * 8 + lane];
      uint4 q3 = Tq[(size_t)csr_src[e + 3] * 8 + lane];
      addq(q0, a0); addq(q1, a1); addq(q2, a2); addq(q3, a3);
    }
    for (; e < hi; ++e) addq(Tq[(size_t)csr_src[e] * 8 + lane], a0);
  }
  float4 bv0 = *(const float4*)&bias[lane * 8];
  float4 bv1 = *(const float4*)&bias[lane * 8 + 4];
  float bb[8] = {bv0.x, bv0.y, bv0.z, bv0.w, bv1.x, bv1.y, bv1.z, bv1.w};
  float h[8];
#pragma unroll
  for (int c = 0; c < 8; ++c)
    h[c] = fmaf(dn, (a0[c] + a1[c]) + (a2[c] + a3[c]), bb[c]);
  float* Hrow = &H[(size_t)node * 64 + lane * 8];
  *(float4*)&Hrow[0] = make_float4(h[0], h[1], h[2], h[3]);
  *(float4*)&Hrow[4] = make_float4(h[4], h[5], h[6], h[7]);
  int k0 = 8 * lane;
  float p0 = 0.f, p1 = 0.f;
#pragma unroll
  for (int c = 0; c < 8; ++c) {
    p0 = fmaf(h[c], Wout[(k0 + c) * 2 + 0], p0);
    p1 = fmaf(h[c], Wout[(k0 + c) * 2 + 1], p1);
  }
#pragma unroll
  for (int off = 4; off >= 1; off >>= 1) {
    p0 += __shfl_xor(p0, off, 8);
    p1 += __shfl_xor(p1, off, 8);
  }
  if (lane == 0) {
    Out[(size_t)node * 2 + 0] = p0 + bout[0];
    Out[(size_t)node * 2 + 1] = p1 + bout[1];
  }
}

extern "C" void kernel_launch(void* const* d_in, const int* in_sizes, int n_in,
                              void* d_out, int out_size, void* d_ws, size_t ws_size,
                              hipStream_t stream) {
  const float* x    = (const float*)d_in[0];
  const int*   ei   = (const int*)d_in[1];
  const float* W1   = (const float*)d_in[2];
  const float* b1   = (const float*)d_in[3];
  const float* W2   = (const float*)d_in[4];
  const float* b2   = (const float*)d_in[5];
  const float* W3   = (const float*)d_in[6];
  const float* b3   = (const float*)d_in[7];
  const float* Wout = (const float*)d_in[8];
  const float* bout = (const float*)d_in[9];

  const int n = NN, E = NE;
  const int* srcp = ei;
  const int* dstp = ei + E;

  char* ws = (char*)d_ws;
  int*    cntmat  = (int*)(ws + 0);            // 1,045,504
  int*    btotal  = (int*)(ws + 1045504);      // -> 1,049,600
  int*    bbase   = (int*)(ws + 1049600);      // -> 1,053,696
  int*    offmat  = (int*)(ws + 1053696);      // -> 2,099,200
  float*  dinv    = (float*)(ws + 2099200);    // -> 2,499,200 (pad 16)
  int*    rcp     = (int*)(ws + 2499216);      // 3.2MB -> 5,699,216
  int*    csr_src = (int*)(ws + 5699216);      // 12.8MB -> 18,499,216
  ushort* WT1     = (ushort*)(ws + 18499216);  // 32KB
  ushort* WT2     = (ushort*)(ws + 18531984);  // 32KB
  ushort* WT3     = (ushort*)(ws + 18564752);  // 16KB -> 18,581,136
  ushort* bufT    = (ushort*)(ws + 18581136);  // 25.6MB -> 44,181,136
  ushort* Pbuf    = (ushort*)(ws + 44181136);  // 8 x 25.6MB -> 248,981,136
  int*    store   = (int*)(ws + 44181136);     // 12.8MB, aliases Pbuf (dead after build)

  const size_t PRIMARY_NEED = 248981136ull;
  bool primary = ws_size >= PRIMARY_NEED;

  float* outp = (float*)d_out;
  float* hemb = (float*)d_out + 2 * n;

  // ---- graph build (atomic-free radix partition, chunk-major CSR) ----
  pcount_kernel<<<NBLK, 256, 0, stream>>>(dstp, cntmat);
  rowsum_kernel<<<NB, 256, 0, stream>>>(cntmat, btotal);
  bucket_scan_kernel<<<1, 1024, 0, stream>>>(btotal, bbase);
  offsets_kernel<<<NB, 256, 0, stream>>>(cntmat, bbase, offmat);
  pscatter_kernel<<<NBLK, 256, 0, stream>>>(srcp, dstp, offmat, store);
  build_kernel<<<NB, 256, 0, stream>>>(btotal, bbase, store, rcp, dinv, csr_src);

  wconv_kernel<<<(128 * 128 + 255) / 256, 256, 0, stream>>>(W1, WT1, 128);
  wconv_kernel<<<(128 * 128 + 255) / 256, 256, 0, stream>>>(W2, WT2, 128);
  wconv_kernel<<<(128 * 64 + 255) / 256, 256, 0, stream>>>(W3, WT3, 64);

  int gemmGrid = (n + 63) / 64;

  if (primary) {
    // layer 1
    gemm_mfma_kernel<128, false><<<gemmGrid, 256, 0, stream>>>(x, WT1, dinv, bufT, n);
    aggp_kernel<16><<<NGRP * 8, 256, 0, stream>>>((const uint4*)bufT, rcp, csr_src, Pbuf, n);
    // layer 2 (fused reduce+GEMM)
    gemm_fused_kernel<128><<<gemmGrid, 256, 0, stream>>>(Pbuf, WT2, dinv, b1, bufT, n);
    aggp_kernel<16><<<NGRP * 8, 256, 0, stream>>>((const uint4*)bufT, rcp, csr_src, Pbuf, n);
    // layer 3 (fused reduce+GEMM, 64ch)
    gemm_fused_kernel<64><<<gemmGrid, 256, 0, stream>>>(Pbuf, WT3, dinv, b2, bufT, n);
    aggp_kernel<8><<<NGRP * 8, 256, 0, stream>>>((const uint4*)bufT, rcp, csr_src, Pbuf, n);
    reduce3_kernel<<<(n * 8 + 255) / 256, 256, 0, stream>>>(Pbuf, dinv, b3, Wout, bout,
                                                            hemb, outp, n);
  } else {
    // fallback: R12 structure (direct gather over rcp segments)
    ushort* bufHb = Pbuf;  // only 25.6MB used
    gemm_mfma_kernel<128, false><<<gemmGrid, 256, 0, stream>>>(x, WT1, dinv, bufT, n);
    agg_fb128_kernel<<<(n * 16 + 255) / 256, 256, 0, stream>>>(
        (const uint4*)bufT, rcp, csr_src, dinv, b1, bufHb, n);
    gemm_mfma_kernel<128, true><<<gemmGrid, 256, 0, stream>>>(bufHb, WT2, dinv, bufT, n);
    agg_fb128_kernel<<<(n * 16 + 255) / 256, 256, 0, stream>>>(
        (const uint4*)bufT, rcp, csr_src, dinv, b2, bufHb, n);
    gemm_mfma_kernel<64, true><<<gemmGrid, 256, 0, stream>>>(bufHb, WT3, dinv, bufT, n);
    agg_fb64_kernel<<<(n * 8 + 255) / 256, 256, 0, stream>>>(
        (const uint4*)bufT, rcp, csr_src, dinv, b3, hemb, Wout, bout, outp, n);
  }
}